// Round 5
// baseline (154.343 us; speedup 1.0000x reference)
//
#include <hip/hip_runtime.h>
#include <hip/hip_bf16.h>
#include <math.h>

// NT-Xent loss, N=4096, D=256. Register-resident-A, barrier-free MFMA version.
// loss = (1/2N) * sum_i [ 2 + log( sum_{j != i} exp(2*dot_ij - 2) ) - 2*dot(zn_i, zn_pair(i)) ]
// K1: normalize rows -> bf16 zn in ws; zero rowtotal[8192] and out.
// K2: 8320 independent wave-units (2080 blocks x 4 waves). Unit = 32 rows x 128
//     cols x full K=256. A fragments live in 64 VGPRs for the whole unit; B
//     fragments stream from L2 with one-tile-ahead register prefetch (8 loads
//     hidden under 32 MFMA = 620 cyc). No LDS, no __syncthreads. exp folded
//     into register row/col partials; shuffle-reduce + global atomics.
// K3: loss += sum_i (2 + log(rowtotal[i])) / 2N.

using short8  = __attribute__((ext_vector_type(8))) short;
using floatx4 = __attribute__((ext_vector_type(4))) float;

constexpr int TWO_N = 8192;
constexpr int DIM   = 256;
constexpr int NUNITS = 8320;            // sum_{b=0}^{255} (64 - (b>>2))
constexpr int NBLK2  = NUNITS / 4;      // 2080
constexpr float INV2N = 1.0f / 8192.0f;

__device__ static inline unsigned short f2bf(float f) {
  unsigned u = __float_as_uint(f);
  return (unsigned short)((u + 0x7fffu + ((u >> 16) & 1u)) >> 16);  // RNE
}

// ---------------- K1: normalize + cast to bf16, zero accumulators ----------------
__global__ __launch_bounds__(256) void k_normalize(
    const float* __restrict__ zi, const float* __restrict__ zj,
    __hip_bfloat16* __restrict__ zn, float* __restrict__ rowtotal,
    float* __restrict__ out)
{
  if (blockIdx.x == 0 && threadIdx.x == 0) out[0] = 0.0f;
  if (blockIdx.x < 32) rowtotal[blockIdx.x * 256 + threadIdx.x] = 0.0f;

  const int lane = threadIdx.x & 63;
  const int wave = threadIdx.x >> 6;
#pragma unroll
  for (int it = 0; it < 8; ++it) {
    const int row = blockIdx.x * 32 + wave * 8 + it;
    const float* src = (row < 4096) ? (zi + (size_t)row * DIM)
                                    : (zj + (size_t)(row - 4096) * DIM);
    float4 v = reinterpret_cast<const float4*>(src)[lane];
    float ss = v.x * v.x + v.y * v.y + v.z * v.z + v.w * v.w;
#pragma unroll
    for (int m = 32; m >= 1; m >>= 1) ss += __shfl_xor(ss, m, 64);
    float inv = 1.0f / fmaxf(sqrtf(ss), 1e-8f);
    ushort4 o;
    o.x = f2bf(v.x * inv); o.y = f2bf(v.y * inv);
    o.z = f2bf(v.z * inv); o.w = f2bf(v.w * inv);
    reinterpret_cast<ushort4*>(zn + (size_t)row * DIM)[lane] = o;
  }
}

// ---------------- K2: barrier-free triangular MFMA + fused epilogue ----------------
__global__ __launch_bounds__(256, 2) void k_simexp(
    const __hip_bfloat16* __restrict__ Z, float* __restrict__ rowtotal,
    float* __restrict__ out)
{
  const int lane = threadIdx.x & 63;
  const int wave = threadIdx.x >> 6;
  const int u = blockIdx.x * 4 + wave;          // unit id, 0..8319

  // decode u -> (b: 32-row band 0..255, c: 128-col block, c >= b>>2)
  // cum(4m) = 258m - 2m^2 ; within group m: 4 bands x w=(64-m) units
  int m = (int)((258.0f - sqrtf(66564.0f - 8.0f * (float)u)) * 0.25f);
  m = (m < 0) ? 0 : ((m > 63) ? 63 : m);
  while (258 * (m + 1) - 2 * (m + 1) * (m + 1) <= u) ++m;
  while (258 * m - 2 * m * m > u) --m;
  const int rem = u - (258 * m - 2 * m * m);
  const int w = 64 - m;
  const int r = (rem >= w) + (rem >= 2 * w) + (rem >= 3 * w);
  const int t = rem - r * w;
  const int b = 4 * m + r;
  const int c = m + t;

  const int i0 = 32 * b;
  const int j0 = 128 * c;
  const bool diag = (c == (b >> 2));
  const bool pair = (c == 32 + (b >> 2)) && (b < 128);

  const int c16 = lane & 15;
  const int q   = lane >> 4;

  const __hip_bfloat16* pA = Z + (size_t)(i0 + c16) * DIM + q * 8;
  const __hip_bfloat16* pB = Z + (size_t)(j0 + c16) * DIM + q * 8;

  // A resident: 2 mt x 8 k-slots x 16B = 64 VGPRs, lives the whole unit
  short8 A[2][8];
#pragma unroll
  for (int mt = 0; mt < 2; ++mt)
#pragma unroll
    for (int s = 0; s < 8; ++s)
      A[mt][s] = *reinterpret_cast<const short8*>(pA + mt * 16 * DIM + s * 32);

  float rowpart[2][4] = {};
  float colpart[8]    = {};
  float pc = 0.0f;

  short8 B0[8], B1[8];
#pragma unroll
  for (int s = 0; s < 8; ++s)
    B0[s] = *reinterpret_cast<const short8*>(pB + s * 32);

  // one nt step: prefetch B for nt+1, 32 MFMA on Bc, fold exp into partials
#define NT_STEP(nt_, Bc_, Bn_)                                                 \
  do {                                                                         \
    if ((nt_) < 7) {                                                           \
      _Pragma("unroll") for (int s = 0; s < 8; ++s)                            \
          Bn_[s] = *reinterpret_cast<const short8*>(                           \
              pB + ((nt_) + 1) * 16 * DIM + s * 32);                           \
    }                                                                          \
    floatx4 acc0 = {}, acc1 = {};                                              \
    _Pragma("unroll") for (int s = 0; s < 8; ++s) {                            \
      acc0 = __builtin_amdgcn_mfma_f32_16x16x32_bf16(A[0][s], Bc_[s], acc0, 0, 0, 0); \
      acc1 = __builtin_amdgcn_mfma_f32_16x16x32_bf16(A[1][s], Bc_[s], acc1, 0, 0, 0); \
    }                                                                          \
    const int j = j0 + (nt_) * 16 + c16;                                       \
    _Pragma("unroll") for (int reg = 0; reg < 4; ++reg) {                      \
      const int ia = i0 + (q << 2) + reg;                                      \
      float v0 = acc0[reg], v1 = acc1[reg];                                    \
      float e0 = __expf(2.0f * v0 - 2.0f);                                     \
      float e1 = __expf(2.0f * v1 - 2.0f);                                     \
      if (diag && j <= ia) e0 = 0.0f;                                          \
      if (diag && j <= ia + 16) e1 = 0.0f;                                     \
      rowpart[0][reg] += e0; rowpart[1][reg] += e1;                            \
      colpart[nt_] += e0 + e1;                                                 \
      if (pair) {                                                              \
        if (j - ia == 4096) pc += v0;                                          \
        if (j - (ia + 16) == 4096) pc += v1;                                   \
      }                                                                        \
    }                                                                          \
  } while (0)

  NT_STEP(0, B0, B1);
  NT_STEP(1, B1, B0);
  NT_STEP(2, B0, B1);
  NT_STEP(3, B1, B0);
  NT_STEP(4, B0, B1);
  NT_STEP(5, B1, B0);
  NT_STEP(6, B0, B1);
  NT_STEP(7, B1, B0);
#undef NT_STEP

  // ---- epilogue: reduce + global atomics (no LDS, no barrier) ----
  // rowpart[mt][reg]: row = i0 + mt*16 + q*4 + reg, summed over lane's 8 cols;
  // reduce over the 16 c16-lanes.
#pragma unroll
  for (int mt = 0; mt < 2; ++mt)
#pragma unroll
    for (int reg = 0; reg < 4; ++reg) {
      float s = rowpart[mt][reg];
      s += __shfl_xor(s, 1, 64);
      s += __shfl_xor(s, 2, 64);
      s += __shfl_xor(s, 4, 64);
      s += __shfl_xor(s, 8, 64);
      if (c16 == 0)
        atomicAdd(&rowtotal[i0 + mt * 16 + (q << 2) + reg], s);
    }
  // colpart[nt]: col = j0 + nt*16 + c16, summed over lane's 8 rows;
  // reduce over the 4 q-lanes.
#pragma unroll
  for (int nt = 0; nt < 8; ++nt) {
    float s = colpart[nt];
    s += __shfl_xor(s, 16, 64);
    s += __shfl_xor(s, 32, 64);
    if (q == 0)
      atomicAdd(&rowtotal[j0 + nt * 16 + c16], s);
  }
  if (pair) {
#pragma unroll
    for (int mm = 32; mm >= 1; mm >>= 1) pc += __shfl_xor(pc, mm, 64);
    // rows i and i+4096 each lose 2*dot -> -4*dot per pair
    if (lane == 0) atomicAdd(out, -4.0f * pc * INV2N);
  }
}

// ---------------- K3: finalize (logs + reduce) ----------------
__global__ __launch_bounds__(256) void k_finalize(
    const float* __restrict__ rowtotal, float* __restrict__ out)
{
  __shared__ float wsum[4];
  const int lane = threadIdx.x & 63;
  const int wave = threadIdx.x >> 6;
  const int row  = blockIdx.x * 256 + threadIdx.x;
  float v = 2.0f + __logf(rowtotal[row]);
#pragma unroll
  for (int m = 32; m >= 1; m >>= 1) v += __shfl_xor(v, m, 64);
  if (lane == 0) wsum[wave] = v;
  __syncthreads();
  if (threadIdx.x == 0)
    atomicAdd(out, (wsum[0] + wsum[1] + wsum[2] + wsum[3]) * INV2N);
}

// ---------------- launch ----------------
extern "C" void kernel_launch(void* const* d_in, const int* in_sizes, int n_in,
                              void* d_out, int out_size, void* d_ws, size_t ws_size,
                              hipStream_t stream) {
  const float* zi = (const float*)d_in[0];
  const float* zj = (const float*)d_in[1];
  float* out = (float*)d_out;

  __hip_bfloat16* zn = (__hip_bfloat16*)d_ws;                        // 8192*256*2 = 4 MB
  float* rowtotal = (float*)((char*)d_ws + (size_t)TWO_N * DIM * 2); // 8192*4 = 32 KB

  k_normalize<<<dim3(256), dim3(256), 0, stream>>>(zi, zj, zn, rowtotal, out);
  k_simexp<<<dim3(NBLK2), dim3(256), 0, stream>>>(zn, rowtotal, out);
  k_finalize<<<dim3(TWO_N / 256), dim3(256), 0, stream>>>(rowtotal, out);
}